// Round 1
// baseline (664.365 us; speedup 1.0000x reference)
//
#include <hip/hip_runtime.h>

typedef unsigned short u16t;
typedef __attribute__((ext_vector_type(8))) short short8;
typedef __attribute__((ext_vector_type(4))) short short4v;
typedef __attribute__((ext_vector_type(4))) float f32x4;
typedef __attribute__((ext_vector_type(4))) unsigned short u16x4;

__device__ __forceinline__ float bf2f(short b) {
  return __uint_as_float(((unsigned)(unsigned short)b) << 16);
}
__device__ __forceinline__ u16t f2bf(float f) {
  unsigned u = __float_as_uint(f);
  u += 0x7FFFu + ((u >> 16) & 1u);  // RNE
  return (u16t)(u >> 16);
}

// jax threefry2x32, key = (0, 42); partitionable counter scheme:
// counter = flat u64 -> (hi=0, lo=flat); bits = o0 ^ o1; keep = top bit 0 (p=0.5)
__device__ __forceinline__ bool keep_mask(unsigned flat) {
  const unsigned k0 = 0u, k1 = 42u;
  const unsigned k2 = k0 ^ k1 ^ 0x1BD11BDAu;
  unsigned x0 = 0u + k0;
  unsigned x1 = flat + k1;
#define TF_R(r) { x0 += x1; x1 = (x1 << r) | (x1 >> (32 - r)); x1 ^= x0; }
  TF_R(13) TF_R(15) TF_R(26) TF_R(6)  x0 += k1; x1 += k2 + 1u;
  TF_R(17) TF_R(29) TF_R(16) TF_R(24) x0 += k2; x1 += k0 + 2u;
  TF_R(13) TF_R(15) TF_R(26) TF_R(6)  x0 += k0; x1 += k1 + 3u;
  TF_R(17) TF_R(29) TF_R(16) TF_R(24) x0 += k1; x1 += k2 + 4u;
  TF_R(13) TF_R(15) TF_R(26) TF_R(6)  x0 += k2; x1 += k0 + 5u;
#undef TF_R
  return ((x0 ^ x1) >> 31) == 0u;
}

__device__ __forceinline__ void load_lds16(const u16t* g, u16t* l) {
  __builtin_amdgcn_global_load_lds((__attribute__((address_space(1))) void*)g,
                                   (__attribute__((address_space(3))) void*)l,
                                   16, 0, 0);
}

// ---- f32 -> bf16 conversion (n divisible by 4) ----
__global__ void cvt_bf16(const float* __restrict__ s, u16t* __restrict__ d, int n) {
  int i = (blockIdx.x * 256 + threadIdx.x) * 4;
  if (i < n) {
    f32x4 v = *(const f32x4*)&s[i];
    u16x4 o = { f2bf(v.x), f2bf(v.y), f2bf(v.z), f2bf(v.w) };
    *(u16x4*)&d[i] = o;
  }
}

// ---- f32 -> bf16 for x, fused with threefry dropout-mask precompute ----
// Thread t (t < nwords) packs keep bits for flat elements [t*32, t*32+32) into mask[t].
// The threefry VALU work hides under this kernel's 150 MB memory stream.
__global__ __launch_bounds__(256) void cvt_x_mask(const float* __restrict__ s,
    u16t* __restrict__ d, unsigned* __restrict__ mask, int n, int nwords) {
  int t = blockIdx.x * 256 + threadIdx.x;
  int i = t * 4;
  if (i < n) {
    f32x4 v = *(const f32x4*)&s[i];
    u16x4 o = { f2bf(v.x), f2bf(v.y), f2bf(v.z), f2bf(v.w) };
    *(u16x4*)&d[i] = o;
  }
  if (t < nwords) {
    unsigned base = (unsigned)t * 32u;
    unsigned m = 0u;
    for (int k = 0; k < 32; ++k) m |= (keep_mask(base + (unsigned)k) ? 1u : 0u) << k;
    mask[t] = m;
  }
}

// ---- CSR build ----
__global__ void count_edges(const int* __restrict__ dst, int E, int* __restrict__ cnt) {
  int e = blockIdx.x * 256 + threadIdx.x;
  if (e < E) atomicAdd(&cnt[dst[e]], 1);
}

__global__ __launch_bounds__(256) void rowp_build(const int* __restrict__ cnt,
    int* __restrict__ rowp, int* __restrict__ cursor, float* __restrict__ dinv,
    int* __restrict__ gctr, int n) {
  __shared__ int sd[256];
  __shared__ int sbase;
  const int tid = threadIdx.x;
  const int i = blockIdx.x * 256 + tid;
  int c = (i < n) ? cnt[i] : 0;
  int v = c;
  sd[tid] = v;
  __syncthreads();
  for (int o = 1; o < 256; o <<= 1) {
    int t = (tid >= o) ? sd[tid - o] : 0;
    __syncthreads();
    v += t;
    sd[tid] = v;
    __syncthreads();
  }
  if (tid == 255) sbase = atomicAdd(gctr, v);
  __syncthreads();
  if (i < n) {
    int start = sbase + v - c;
    rowp[i] = start;
    cursor[i] = start;
    dinv[i] = rsqrtf((float)(c + 1));  // +1 self loop
  }
}

// col stored as u16 (node ids < 65536): halves CSR stream bytes for the sliced passes
__global__ void fill_csr(const int* __restrict__ src, const int* __restrict__ dst, int E,
                         int* __restrict__ cursor, u16t* __restrict__ col) {
  int e = blockIdx.x * 256 + threadIdx.x;
  if (e < E) {
    int d = dst[e];
    int pos = atomicAdd(&cursor[d], 1);
    col[pos] = (u16t)src[e];
  }
}

// ---- m97-style bf16 GEMM with SLICE-MAJOR output:
// C layout: [Ncols/32][Mrows][32] so each 32-feature slice is a contiguous
// 3.2 MB table (fits one XCD's 4 MiB L2 during the sliced propagate).
__global__ __launch_bounds__(256) void gemm_bt_sl(const u16t* __restrict__ A,
                                                  const u16t* __restrict__ B,
                                                  u16t* __restrict__ C,
                                                  int K, int Mrows) {
  __shared__ __align__(16) u16t lA[128 * 32];
  __shared__ __align__(16) u16t lB[128 * 32];
  const int tid = threadIdx.x;
  const int wave = tid >> 6, lane = tid & 63;
  const int wm = (wave & 1) * 64, wn = (wave >> 1) * 64;
  const int lrow = lane & 15, lq = lane >> 4;
  const u16t* Ab = A + (size_t)blockIdx.x * 128 * K;
  const u16t* Bb = B + (size_t)blockIdx.y * 128 * K;
  const int r0 = tid >> 2, c0 = (tid & 3) * 8;
  const int ldsOff = __builtin_amdgcn_readfirstlane((tid >> 6) * 512);

  f32x4 acc[4][4];
  const f32x4 zero = {0.f, 0.f, 0.f, 0.f};
#pragma unroll
  for (int mi = 0; mi < 4; ++mi)
#pragma unroll
    for (int ni = 0; ni < 4; ++ni) acc[mi][ni] = zero;

  for (int kt = 0; kt < K; kt += 32) {
    __syncthreads();
    load_lds16(Ab + (size_t)r0 * K + kt + c0, &lA[ldsOff]);
    load_lds16(Ab + (size_t)(r0 + 64) * K + kt + c0, &lA[2048 + ldsOff]);
    load_lds16(Bb + (size_t)r0 * K + kt + c0, &lB[ldsOff]);
    load_lds16(Bb + (size_t)(r0 + 64) * K + kt + c0, &lB[2048 + ldsOff]);
    __syncthreads();
    short8 af[4], bfr[4];
#pragma unroll
    for (int mi = 0; mi < 4; ++mi)
      af[mi] = *(const short8*)&lA[(wm + mi * 16 + lrow) * 32 + lq * 8];
#pragma unroll
    for (int ni = 0; ni < 4; ++ni)
      bfr[ni] = *(const short8*)&lB[(wn + ni * 16 + lrow) * 32 + lq * 8];
#pragma unroll
    for (int mi = 0; mi < 4; ++mi)
#pragma unroll
      for (int ni = 0; ni < 4; ++ni)
        acc[mi][ni] = __builtin_amdgcn_mfma_f32_16x16x32_bf16(af[mi], bfr[ni], acc[mi][ni], 0, 0, 0);
  }

  const int crow0 = blockIdx.x * 128 + wm + lq * 4;
  const int ccol0 = blockIdx.y * 128 + wn + lrow;
#pragma unroll
  for (int mi = 0; mi < 4; ++mi)
#pragma unroll
    for (int r = 0; r < 4; ++r)
#pragma unroll
      for (int ni = 0; ni < 4; ++ni) {
        int cc = ccol0 + ni * 16;
        size_t idx = ((size_t)(cc >> 5) * Mrows + (crow0 + mi * 16 + r)) * 32 + (cc & 31);
        C[idx] = f2bf(acc[mi][ni][r]);
      }
}

// ---- sliced propagate layer 1 ----
// Grid: 2 phases x 8 xcd-slices x chunks. slice = (bid%8) + 8*phase so each XCD
// (blockIdx round-robin) keeps exactly one 3.2 MB slice table L2-resident.
// Block = 256 thr = 32 nodes; each 8-lane group owns one node (4 feats/lane).
__global__ __launch_bounds__(256) void prop1_kernel(const u16t* __restrict__ y1s,
    const u16t* __restrict__ colu, const int* __restrict__ rowp, const int* __restrict__ rowend,
    const float* __restrict__ dinv, const float* __restrict__ b1,
    const unsigned* __restrict__ kmask,
    float* __restrict__ embf, u16t* __restrict__ embb, int n, int Mrows, int chunks) {
  const int t = threadIdx.x;
  const int fl4 = (t & 7) * 4;
  const int bid = blockIdx.x;
  const int half = chunks << 3;
  const int phase = bid >= half;
  const int rem = bid - (phase ? half : 0);
  const int sl = (rem & 7) + (phase << 3);
  const int i = (rem >> 3) * 32 + (t >> 3);
  if (i >= n) return;

  const u16t* T = y1s + (size_t)sl * Mrows * 32;
  const float di = dinv[i];
  float acc[4];
  {
    short4v u = *(const short4v*)&T[(size_t)i * 32 + fl4];
#pragma unroll
    for (int j = 0; j < 4; ++j) acc[j] = di * bf2f(u[j]);
  }
  int e = rowp[i];
  const int e1 = rowend[i];
  for (; e + 4 <= e1; e += 4) {
    const int s0 = (int)colu[e], s1 = (int)colu[e + 1];
    const int s2 = (int)colu[e + 2], s3 = (int)colu[e + 3];
    const float w0 = dinv[s0], w1 = dinv[s1], w2 = dinv[s2], w3 = dinv[s3];
    short4v u0 = *(const short4v*)&T[(size_t)s0 * 32 + fl4];
    short4v u1 = *(const short4v*)&T[(size_t)s1 * 32 + fl4];
    short4v u2 = *(const short4v*)&T[(size_t)s2 * 32 + fl4];
    short4v u3 = *(const short4v*)&T[(size_t)s3 * 32 + fl4];
#pragma unroll
    for (int j = 0; j < 4; ++j) acc[j] += w0 * bf2f(u0[j]);
#pragma unroll
    for (int j = 0; j < 4; ++j) acc[j] += w1 * bf2f(u1[j]);
#pragma unroll
    for (int j = 0; j < 4; ++j) acc[j] += w2 * bf2f(u2[j]);
#pragma unroll
    for (int j = 0; j < 4; ++j) acc[j] += w3 * bf2f(u3[j]);
  }
  for (; e < e1; ++e) {
    const int s = (int)colu[e];
    const float w = dinv[s];
    short4v u = *(const short4v*)&T[(size_t)s * 32 + fl4];
#pragma unroll
    for (int j = 0; j < 4; ++j) acc[j] += w * bf2f(u[j]);
  }

  const int f = sl * 32 + fl4;
  const unsigned km = kmask[i * 16 + sl];
  f32x4 o;
  short4v ob;
#pragma unroll
  for (int j = 0; j < 4; ++j) {
    float h = di * acc[j] + b1[f + j];
    h = fmaxf(h, 0.f);
    float eb = ((km >> (fl4 + j)) & 1u) ? 2.f * h : 0.f;
    o[j] = eb;
    ob[j] = (short)f2bf(eb);
  }
  // nontemporal: keep the 153 MB output stream from evicting the slice table
  __builtin_nontemporal_store(o, (f32x4*)&embf[(size_t)i * 512 + f]);
  __builtin_nontemporal_store(ob, (short4v*)&embb[(size_t)i * 512 + f]);
}

// ---- sliced propagate layer 2 (8 slices, 1 phase) ----
__global__ __launch_bounds__(256) void prop2_kernel(const u16t* __restrict__ zs,
    const u16t* __restrict__ colu, const int* __restrict__ rowp, const int* __restrict__ rowend,
    const float* __restrict__ dinv, const float* __restrict__ b2,
    float* __restrict__ outp, int n, int Mrows, int chunks) {
  const int t = threadIdx.x;
  const int fl4 = (t & 7) * 4;
  const int bid = blockIdx.x;
  const int sl = bid & 7;
  const int i = (bid >> 3) * 32 + (t >> 3);
  (void)chunks;
  if (i >= n) return;

  const u16t* T = zs + (size_t)sl * Mrows * 32;
  const float di = dinv[i];
  float acc[4];
  {
    short4v u = *(const short4v*)&T[(size_t)i * 32 + fl4];
#pragma unroll
    for (int j = 0; j < 4; ++j) acc[j] = di * bf2f(u[j]);
  }
  int e = rowp[i];
  const int e1 = rowend[i];
  for (; e + 4 <= e1; e += 4) {
    const int s0 = (int)colu[e], s1 = (int)colu[e + 1];
    const int s2 = (int)colu[e + 2], s3 = (int)colu[e + 3];
    const float w0 = dinv[s0], w1 = dinv[s1], w2 = dinv[s2], w3 = dinv[s3];
    short4v u0 = *(const short4v*)&T[(size_t)s0 * 32 + fl4];
    short4v u1 = *(const short4v*)&T[(size_t)s1 * 32 + fl4];
    short4v u2 = *(const short4v*)&T[(size_t)s2 * 32 + fl4];
    short4v u3 = *(const short4v*)&T[(size_t)s3 * 32 + fl4];
#pragma unroll
    for (int j = 0; j < 4; ++j) acc[j] += w0 * bf2f(u0[j]);
#pragma unroll
    for (int j = 0; j < 4; ++j) acc[j] += w1 * bf2f(u1[j]);
#pragma unroll
    for (int j = 0; j < 4; ++j) acc[j] += w2 * bf2f(u2[j]);
#pragma unroll
    for (int j = 0; j < 4; ++j) acc[j] += w3 * bf2f(u3[j]);
  }
  for (; e < e1; ++e) {
    const int s = (int)colu[e];
    const float w = dinv[s];
    short4v u = *(const short4v*)&T[(size_t)s * 32 + fl4];
#pragma unroll
    for (int j = 0; j < 4; ++j) acc[j] += w * bf2f(u[j]);
  }

  const int f = sl * 32 + fl4;
  f32x4 o;
#pragma unroll
  for (int j = 0; j < 4; ++j) o[j] = di * acc[j] + b2[f + j];
  __builtin_nontemporal_store(o, (f32x4*)&outp[(size_t)i * 256 + f]);
}

extern "C" void kernel_launch(void* const* d_in, const int* in_sizes, int n_in,
                              void* d_out, int out_size, void* d_ws, size_t ws_size,
                              hipStream_t stream) {
  (void)n_in; (void)out_size; (void)ws_size;
  const float* x  = (const float*)d_in[0];
  const int*   ei = (const int*)d_in[1];    // [2][E]: src row then dst row
  const float* W1 = (const float*)d_in[2];
  const float* b1 = (const float*)d_in[3];
  const float* W2 = (const float*)d_in[4];
  const float* b2 = (const float*)d_in[5];

  const int Nn = in_sizes[0] / 512;             // 50000
  const int E  = in_sizes[1] / 2;               // 800000
  const int Mpad = ((Nn + 127) / 128) * 128;    // 50048
  const int K = 512;
  const int CH = (Nn + 31) / 32;                // node chunks of 32

  char* ws = (char*)d_ws;
  size_t off = 0;
  auto take = [&](size_t bytes) -> char* {
    char* p = ws + off;
    off += (bytes + 255) & ~(size_t)255;
    return p;
  };
  u16t* xb   = (u16t*)take((size_t)Mpad * 512 * 2);      // x bf16; later reused as emb bf16
  u16t* y1s  = (u16t*)take((size_t)16 * Mpad * 32 * 2);  // y1 slice-major; zs aliases front half
  u16t* W1b  = (u16t*)take((size_t)512 * 512 * 2);
  u16t* W2b  = (u16t*)take((size_t)256 * 512 * 2);
  int*   cnt    = (int*)take((size_t)(Nn + 1) * 4);      // cnt[Nn] is the global cursor
  int*   rowp   = (int*)take((size_t)Nn * 4);
  int*   cursor = (int*)take((size_t)Nn * 4);
  float* dinv   = (float*)take((size_t)Nn * 4);
  u16t*  colu   = (u16t*)take((size_t)E * 2);
  unsigned* kmask = (unsigned*)take((size_t)Nn * 16 * 4);  // 32 keep-bits per (node,slice)

  float* embf = (float*)d_out;                       // [Nn,512]
  float* outf = (float*)d_out + (size_t)Nn * 512;    // [Nn,256]

  hipMemsetAsync(cnt, 0, (size_t)(Nn + 1) * 4, stream);

  const int n1 = Nn * 512;
  cvt_x_mask<<<(n1 / 4 + 255) / 256, 256, 0, stream>>>(x, xb, kmask, n1, Nn * 16);
  cvt_bf16<<<(512 * 512 / 4 + 255) / 256, 256, 0, stream>>>(W1, W1b, 512 * 512);
  cvt_bf16<<<(256 * 512 / 4 + 255) / 256, 256, 0, stream>>>(W2, W2b, 256 * 512);

  count_edges<<<(E + 255) / 256, 256, 0, stream>>>(ei + E, E, cnt);
  rowp_build<<<(Nn + 255) / 256, 256, 0, stream>>>(cnt, rowp, cursor, dinv, cnt + Nn, Nn);
  fill_csr<<<(E + 255) / 256, 256, 0, stream>>>(ei, ei + E, E, cursor, colu);

  // layer 1: y1 = x @ W1^T (bf16, slice-major), then XCD-sliced propagate
  dim3 g1(Mpad / 128, 4);
  gemm_bt_sl<<<g1, 256, 0, stream>>>(xb, W1b, y1s, K, Mpad);
  prop1_kernel<<<16 * CH, 256, 0, stream>>>(y1s, colu, rowp, cursor, dinv, b1, kmask,
                                            embf, xb /* emb bf16, aliases xb */, Nn, Mpad, CH);

  // layer 2: z = emb @ W2^T (bf16, slice-major), then XCD-sliced propagate + b2
  u16t* zs = y1s;  // alias: y1 dead after prop1
  dim3 g2(Mpad / 128, 2);
  gemm_bt_sl<<<g2, 256, 0, stream>>>(xb, W2b, zs, K, Mpad);
  prop2_kernel<<<8 * CH, 256, 0, stream>>>(zs, colu, rowp, cursor, dinv, b2, outf, Nn, Mpad, CH);
}

// Round 2
// 603.441 us; speedup vs baseline: 1.1010x; 1.1010x over previous
//
#include <hip/hip_runtime.h>

typedef unsigned short u16t;
typedef __attribute__((ext_vector_type(8))) short short8;
typedef __attribute__((ext_vector_type(4))) short short4v;
typedef __attribute__((ext_vector_type(4))) float f32x4;
typedef __attribute__((ext_vector_type(4))) unsigned short u16x4;

__device__ __forceinline__ float bf2f(short b) {
  return __uint_as_float(((unsigned)(unsigned short)b) << 16);
}
__device__ __forceinline__ u16t f2bf(float f) {
  unsigned u = __float_as_uint(f);
  u += 0x7FFFu + ((u >> 16) & 1u);  // RNE
  return (u16t)(u >> 16);
}

// jax threefry2x32, key = (0, 42); partitionable counter scheme:
// counter = flat u64 -> (hi=0, lo=flat); bits = o0 ^ o1; keep = top bit 0 (p=0.5)
__device__ __forceinline__ bool keep_mask(unsigned flat) {
  const unsigned k0 = 0u, k1 = 42u;
  const unsigned k2 = k0 ^ k1 ^ 0x1BD11BDAu;
  unsigned x0 = 0u + k0;
  unsigned x1 = flat + k1;
#define TF_R(r) { x0 += x1; x1 = (x1 << r) | (x1 >> (32 - r)); x1 ^= x0; }
  TF_R(13) TF_R(15) TF_R(26) TF_R(6)  x0 += k1; x1 += k2 + 1u;
  TF_R(17) TF_R(29) TF_R(16) TF_R(24) x0 += k2; x1 += k0 + 2u;
  TF_R(13) TF_R(15) TF_R(26) TF_R(6)  x0 += k0; x1 += k1 + 3u;
  TF_R(17) TF_R(29) TF_R(16) TF_R(24) x0 += k1; x1 += k2 + 4u;
  TF_R(13) TF_R(15) TF_R(26) TF_R(6)  x0 += k2; x1 += k0 + 5u;
#undef TF_R
  return ((x0 ^ x1) >> 31) == 0u;
}

__device__ __forceinline__ void load_lds16(const u16t* g, u16t* l) {
  __builtin_amdgcn_global_load_lds((__attribute__((address_space(1))) void*)g,
                                   (__attribute__((address_space(3))) void*)l,
                                   16, 0, 0);
}

// ---- f32 -> bf16 conversion (n divisible by 4) ----
__global__ void cvt_bf16(const float* __restrict__ s, u16t* __restrict__ d, int n) {
  int i = (blockIdx.x * 256 + threadIdx.x) * 4;
  if (i < n) {
    f32x4 v = *(const f32x4*)&s[i];
    u16x4 o = { f2bf(v.x), f2bf(v.y), f2bf(v.z), f2bf(v.w) };
    *(u16x4*)&d[i] = o;
  }
}

// ---- f32 -> bf16 for x, fused with threefry dropout-mask precompute ----
__global__ __launch_bounds__(256) void cvt_x_mask(const float* __restrict__ s,
    u16t* __restrict__ d, unsigned* __restrict__ mask, int n, int nwords) {
  int t = blockIdx.x * 256 + threadIdx.x;
  int i = t * 4;
  if (i < n) {
    f32x4 v = *(const f32x4*)&s[i];
    u16x4 o = { f2bf(v.x), f2bf(v.y), f2bf(v.z), f2bf(v.w) };
    *(u16x4*)&d[i] = o;
  }
  if (t < nwords) {
    unsigned base = (unsigned)t * 32u;
    unsigned m = 0u;
    for (int k = 0; k < 32; ++k) m |= (keep_mask(base + (unsigned)k) ? 1u : 0u) << k;
    mask[t] = m;
  }
}

// ---- CSR build ----
__global__ void count_edges(const int* __restrict__ dst, int E, int* __restrict__ cnt) {
  int e = blockIdx.x * 256 + threadIdx.x;
  if (e < E) atomicAdd(&cnt[dst[e]], 1);
}

__global__ __launch_bounds__(256) void rowp_build(const int* __restrict__ cnt,
    int* __restrict__ rowp, int* __restrict__ cursor, float* __restrict__ dinv,
    int* __restrict__ gctr, int n) {
  __shared__ int sd[256];
  __shared__ int sbase;
  const int tid = threadIdx.x;
  const int i = blockIdx.x * 256 + tid;
  int c = (i < n) ? cnt[i] : 0;
  int v = c;
  sd[tid] = v;
  __syncthreads();
  for (int o = 1; o < 256; o <<= 1) {
    int t = (tid >= o) ? sd[tid - o] : 0;
    __syncthreads();
    v += t;
    sd[tid] = v;
    __syncthreads();
  }
  if (tid == 255) sbase = atomicAdd(gctr, v);
  __syncthreads();
  if (i < n) {
    int start = sbase + v - c;
    rowp[i] = start;
    cursor[i] = start;
    dinv[i] = rsqrtf((float)(c + 1));  // +1 self loop
  }
}

// col stored as u16 (node ids < 65536)
__global__ void fill_csr(const int* __restrict__ src, const int* __restrict__ dst, int E,
                         int* __restrict__ cursor, u16t* __restrict__ col) {
  int e = blockIdx.x * 256 + threadIdx.x;
  if (e < E) {
    int d = dst[e];
    int pos = atomicAdd(&cursor[d], 1);
    col[pos] = (u16t)src[e];
  }
}

// ---- m97-style bf16 GEMM, SLICE-MAJOR output, rows PRE-SCALED by dinv[row]:
// C layout: [Ncols/32][Mrows][32]; C[row] = dinv[row] * (A[row] @ B^T).
// Pre-scaling folds the gather-side norm weight into the table, so the
// propagate inner loop needs NO dinv gather and NO multiply per edge.
__global__ __launch_bounds__(256) void gemm_bt_sl(const u16t* __restrict__ A,
                                                  const u16t* __restrict__ B,
                                                  u16t* __restrict__ C,
                                                  int K, int Mrows,
                                                  const float* __restrict__ dinv,
                                                  int Nclamp) {
  __shared__ __align__(16) u16t lA[128 * 32];
  __shared__ __align__(16) u16t lB[128 * 32];
  const int tid = threadIdx.x;
  const int wave = tid >> 6, lane = tid & 63;
  const int wm = (wave & 1) * 64, wn = (wave >> 1) * 64;
  const int lrow = lane & 15, lq = lane >> 4;
  const u16t* Ab = A + (size_t)blockIdx.x * 128 * K;
  const u16t* Bb = B + (size_t)blockIdx.y * 128 * K;
  const int r0 = tid >> 2, c0 = (tid & 3) * 8;
  const int ldsOff = __builtin_amdgcn_readfirstlane((tid >> 6) * 512);

  f32x4 acc[4][4];
  const f32x4 zero = {0.f, 0.f, 0.f, 0.f};
#pragma unroll
  for (int mi = 0; mi < 4; ++mi)
#pragma unroll
    for (int ni = 0; ni < 4; ++ni) acc[mi][ni] = zero;

  for (int kt = 0; kt < K; kt += 32) {
    __syncthreads();
    load_lds16(Ab + (size_t)r0 * K + kt + c0, &lA[ldsOff]);
    load_lds16(Ab + (size_t)(r0 + 64) * K + kt + c0, &lA[2048 + ldsOff]);
    load_lds16(Bb + (size_t)r0 * K + kt + c0, &lB[ldsOff]);
    load_lds16(Bb + (size_t)(r0 + 64) * K + kt + c0, &lB[2048 + ldsOff]);
    __syncthreads();
    short8 af[4], bfr[4];
#pragma unroll
    for (int mi = 0; mi < 4; ++mi)
      af[mi] = *(const short8*)&lA[(wm + mi * 16 + lrow) * 32 + lq * 8];
#pragma unroll
    for (int ni = 0; ni < 4; ++ni)
      bfr[ni] = *(const short8*)&lB[(wn + ni * 16 + lrow) * 32 + lq * 8];
#pragma unroll
    for (int mi = 0; mi < 4; ++mi)
#pragma unroll
      for (int ni = 0; ni < 4; ++ni)
        acc[mi][ni] = __builtin_amdgcn_mfma_f32_16x16x32_bf16(af[mi], bfr[ni], acc[mi][ni], 0, 0, 0);
  }

  const int crow0 = blockIdx.x * 128 + wm + lq * 4;
  const int ccol0 = blockIdx.y * 128 + wn + lrow;
#pragma unroll
  for (int mi = 0; mi < 4; ++mi)
#pragma unroll
    for (int r = 0; r < 4; ++r) {
      const int row = crow0 + mi * 16 + r;
      const float dr = dinv[row < Nclamp ? row : 0];  // padded rows: garbage, never read
#pragma unroll
      for (int ni = 0; ni < 4; ++ni) {
        int cc = ccol0 + ni * 16;
        size_t idx = ((size_t)(cc >> 5) * Mrows + row) * 32 + (cc & 31);
        C[idx] = f2bf(dr * acc[mi][ni][r]);
      }
    }
}

// ---- sliced propagate layer 1 ----
// Table rows are pre-scaled by dinv[src]: inner loop is acc += T[col], nothing else.
// 8-edge chunks with next-chunk col preload (software pipeline) so the col->gather
// dependent chain exposes ~1 L2 latency per 8 edges.
__global__ __launch_bounds__(256) void prop1_kernel(const u16t* __restrict__ y1s,
    const u16t* __restrict__ colu, const int* __restrict__ rowp, const int* __restrict__ rowend,
    const float* __restrict__ dinv, const float* __restrict__ b1,
    const unsigned* __restrict__ kmask,
    float* __restrict__ embf, u16t* __restrict__ embb, int n, int Mrows, int chunks) {
  const int t = threadIdx.x;
  const int fl4 = (t & 7) * 4;
  const int bid = blockIdx.x;
  const int half = chunks << 3;
  const int phase = bid >= half;
  const int rem = bid - (phase ? half : 0);
  const int sl = (rem & 7) + (phase << 3);
  const int i = (rem >> 3) * 32 + (t >> 3);
  if (i >= n) return;

  const u16t* T = y1s + (size_t)sl * Mrows * 32 + fl4;
  const float di = dinv[i];
  float acc[4];
  {
    short4v u = *(const short4v*)&T[(size_t)i * 32];
#pragma unroll
    for (int j = 0; j < 4; ++j) acc[j] = bf2f(u[j]);  // T already includes dinv[i]
  }
  int e = rowp[i];
  const int e1 = rowend[i];
  if (e + 8 <= e1) {
    int c[8];
#pragma unroll
    for (int q = 0; q < 8; ++q) c[q] = (int)colu[e + q];
    e += 8;
    while (e + 8 <= e1) {
      int c2[8];
#pragma unroll
      for (int q = 0; q < 8; ++q) c2[q] = (int)colu[e + q];
#pragma unroll
      for (int q = 0; q < 8; ++q) {
        short4v u = *(const short4v*)&T[(size_t)c[q] * 32];
#pragma unroll
        for (int j = 0; j < 4; ++j) acc[j] += bf2f(u[j]);
      }
#pragma unroll
      for (int q = 0; q < 8; ++q) c[q] = c2[q];
      e += 8;
    }
#pragma unroll
    for (int q = 0; q < 8; ++q) {
      short4v u = *(const short4v*)&T[(size_t)c[q] * 32];
#pragma unroll
      for (int j = 0; j < 4; ++j) acc[j] += bf2f(u[j]);
    }
  }
  for (; e < e1; ++e) {
    short4v u = *(const short4v*)&T[(size_t)(int)colu[e] * 32];
#pragma unroll
    for (int j = 0; j < 4; ++j) acc[j] += bf2f(u[j]);
  }

  const int f = sl * 32 + fl4;
  const unsigned km = kmask[i * 16 + sl];
  f32x4 o;
  short4v ob;
#pragma unroll
  for (int j = 0; j < 4; ++j) {
    float h = di * acc[j] + b1[f + j];
    h = fmaxf(h, 0.f);
    float eb = ((km >> (fl4 + j)) & 1u) ? 2.f * h : 0.f;
    o[j] = eb;
    ob[j] = (short)f2bf(eb);
  }
  __builtin_nontemporal_store(o, (f32x4*)&embf[(size_t)i * 512 + f]);
  __builtin_nontemporal_store(ob, (short4v*)&embb[(size_t)i * 512 + f]);
}

// ---- sliced propagate layer 2 (8 slices, 1 phase) ----
__global__ __launch_bounds__(256) void prop2_kernel(const u16t* __restrict__ zs,
    const u16t* __restrict__ colu, const int* __restrict__ rowp, const int* __restrict__ rowend,
    const float* __restrict__ dinv, const float* __restrict__ b2,
    float* __restrict__ outp, int n, int Mrows, int chunks) {
  const int t = threadIdx.x;
  const int fl4 = (t & 7) * 4;
  const int bid = blockIdx.x;
  const int sl = bid & 7;
  const int i = (bid >> 3) * 32 + (t >> 3);
  (void)chunks;
  if (i >= n) return;

  const u16t* T = zs + (size_t)sl * Mrows * 32 + fl4;
  const float di = dinv[i];
  float acc[4];
  {
    short4v u = *(const short4v*)&T[(size_t)i * 32];
#pragma unroll
    for (int j = 0; j < 4; ++j) acc[j] = bf2f(u[j]);
  }
  int e = rowp[i];
  const int e1 = rowend[i];
  if (e + 8 <= e1) {
    int c[8];
#pragma unroll
    for (int q = 0; q < 8; ++q) c[q] = (int)colu[e + q];
    e += 8;
    while (e + 8 <= e1) {
      int c2[8];
#pragma unroll
      for (int q = 0; q < 8; ++q) c2[q] = (int)colu[e + q];
#pragma unroll
      for (int q = 0; q < 8; ++q) {
        short4v u = *(const short4v*)&T[(size_t)c[q] * 32];
#pragma unroll
        for (int j = 0; j < 4; ++j) acc[j] += bf2f(u[j]);
      }
#pragma unroll
      for (int q = 0; q < 8; ++q) c[q] = c2[q];
      e += 8;
    }
#pragma unroll
    for (int q = 0; q < 8; ++q) {
      short4v u = *(const short4v*)&T[(size_t)c[q] * 32];
#pragma unroll
      for (int j = 0; j < 4; ++j) acc[j] += bf2f(u[j]);
    }
  }
  for (; e < e1; ++e) {
    short4v u = *(const short4v*)&T[(size_t)(int)colu[e] * 32];
#pragma unroll
    for (int j = 0; j < 4; ++j) acc[j] += bf2f(u[j]);
  }

  const int f = sl * 32 + fl4;
  f32x4 o;
#pragma unroll
  for (int j = 0; j < 4; ++j) o[j] = di * acc[j] + b2[f + j];
  __builtin_nontemporal_store(o, (f32x4*)&outp[(size_t)i * 256 + f]);
}

extern "C" void kernel_launch(void* const* d_in, const int* in_sizes, int n_in,
                              void* d_out, int out_size, void* d_ws, size_t ws_size,
                              hipStream_t stream) {
  (void)n_in; (void)out_size; (void)ws_size;
  const float* x  = (const float*)d_in[0];
  const int*   ei = (const int*)d_in[1];    // [2][E]: src row then dst row
  const float* W1 = (const float*)d_in[2];
  const float* b1 = (const float*)d_in[3];
  const float* W2 = (const float*)d_in[4];
  const float* b2 = (const float*)d_in[5];

  const int Nn = in_sizes[0] / 512;             // 50000
  const int E  = in_sizes[1] / 2;               // 800000
  const int Mpad = ((Nn + 127) / 128) * 128;    // 50048
  const int K = 512;
  const int CH = (Nn + 31) / 32;                // node chunks of 32

  char* ws = (char*)d_ws;
  size_t off = 0;
  auto take = [&](size_t bytes) -> char* {
    char* p = ws + off;
    off += (bytes + 255) & ~(size_t)255;
    return p;
  };
  u16t* xb   = (u16t*)take((size_t)Mpad * 512 * 2);      // x bf16; later reused as emb bf16
  u16t* y1s  = (u16t*)take((size_t)16 * Mpad * 32 * 2);  // y1 slice-major; zs aliases front half
  u16t* W1b  = (u16t*)take((size_t)512 * 512 * 2);
  u16t* W2b  = (u16t*)take((size_t)256 * 512 * 2);
  int*   cnt    = (int*)take((size_t)(Nn + 1) * 4);      // cnt[Nn] is the global cursor
  int*   rowp   = (int*)take((size_t)Nn * 4);
  int*   cursor = (int*)take((size_t)Nn * 4);
  float* dinv   = (float*)take((size_t)Nn * 4);
  u16t*  colu   = (u16t*)take((size_t)E * 2);
  unsigned* kmask = (unsigned*)take((size_t)Nn * 16 * 4);  // 32 keep-bits per (node,slice)

  float* embf = (float*)d_out;                       // [Nn,512]
  float* outf = (float*)d_out + (size_t)Nn * 512;    // [Nn,256]

  hipMemsetAsync(cnt, 0, (size_t)(Nn + 1) * 4, stream);

  const int n1 = Nn * 512;
  cvt_x_mask<<<(n1 / 4 + 255) / 256, 256, 0, stream>>>(x, xb, kmask, n1, Nn * 16);
  cvt_bf16<<<(512 * 512 / 4 + 255) / 256, 256, 0, stream>>>(W1, W1b, 512 * 512);
  cvt_bf16<<<(256 * 512 / 4 + 255) / 256, 256, 0, stream>>>(W2, W2b, 256 * 512);

  count_edges<<<(E + 255) / 256, 256, 0, stream>>>(ei + E, E, cnt);
  rowp_build<<<(Nn + 255) / 256, 256, 0, stream>>>(cnt, rowp, cursor, dinv, cnt + Nn, Nn);
  fill_csr<<<(E + 255) / 256, 256, 0, stream>>>(ei, ei + E, E, cursor, colu);

  // layer 1: y1 = dinv * (x @ W1^T) (bf16, slice-major, pre-scaled), then sliced propagate
  dim3 g1(Mpad / 128, 4);
  gemm_bt_sl<<<g1, 256, 0, stream>>>(xb, W1b, y1s, K, Mpad, dinv, Nn);
  prop1_kernel<<<16 * CH, 256, 0, stream>>>(y1s, colu, rowp, cursor, dinv, b1, kmask,
                                            embf, xb /* emb bf16, aliases xb */, Nn, Mpad, CH);

  // layer 2: z = dinv * (emb @ W2^T) (bf16, slice-major, pre-scaled), then propagate + b2
  u16t* zs = y1s;  // alias: y1 dead after prop1
  dim3 g2(Mpad / 128, 2);
  gemm_bt_sl<<<g2, 256, 0, stream>>>(xb, W2b, zs, K, Mpad, dinv, Nn);
  prop2_kernel<<<8 * CH, 256, 0, stream>>>(zs, colu, rowp, cursor, dinv, b2, outf, Nn, Mpad, CH);
}